// Round 7
// baseline (202.921 us; speedup 1.0000x reference)
//
#include <hip/hip_runtime.h>

#define DEV __device__ __forceinline__

typedef float f32x4 __attribute__((ext_vector_type(4)));
typedef short short4v __attribute__((ext_vector_type(4)));
typedef short short8v __attribute__((ext_vector_type(8)));
typedef __bf16 bf16x8 __attribute__((ext_vector_type(8)));

#define QKSTR (2048L * 2048)
#define PSTR  (2048L * 2048)
#define OSTR  (2048L * 1024)

DEV unsigned short f2bf(float f) {
  unsigned int u = __float_as_uint(f);
  u += 0x7fffu + ((u >> 16) & 1u);   // round-to-nearest-even
  return (unsigned short)(u >> 16);
}
DEV float bf2f(short s) {
  return __uint_as_float(((unsigned int)(unsigned short)s) << 16);
}

DEV void async16(void* lds, const void* g) {
  __builtin_amdgcn_global_load_lds((const __attribute__((address_space(1))) void*)g,
                                   (__attribute__((address_space(3))) void*)lds, 16, 0, 0);
}

DEV void store_elem(float* C, long i, float v) { C[i] = v; }
DEV void store_elem(short* C, long i, float v) { C[i] = (short)f2bf(v); }

// ---------------- fused prologue: cast x, transpose 3 W's, concat biases ----------------
__global__ void pre_kernel(const float* __restrict__ x, short* __restrict__ xb,
                           const float* __restrict__ Wq, const float* __restrict__ Wk,
                           const float* __restrict__ Wv, short* __restrict__ wqkt,
                           short* __restrict__ wvt,
                           const float* __restrict__ bq, const float* __restrict__ bk,
                           float* __restrict__ bqk)
{
  __shared__ float t[32][33];
  const int b = blockIdx.x;
  if (b < 4096) {                    // cast x -> bf16, 8 elems/thread
    long i = ((long)b * 256 + threadIdx.x) * 8;
    f32x4 a = *(const f32x4*)(x + i);
    f32x4 c = *(const f32x4*)(x + i + 4);
    short8v o;
#pragma unroll
    for (int j = 0; j < 4; ++j) { o[j] = (short)f2bf(a[j]); o[4 + j] = (short)f2bf(c[j]); }
    *(short8v*)(xb + i) = o;
  } else if (b < 7168) {             // transpose+cast one 32x32 tile of a W
    int tb = b - 4096;
    int which = tb >> 10;
    int t2 = tb & 1023;
    const float* W = (which == 0) ? Wq : (which == 1) ? Wk : Wv;
    short* Wt = (which == 0) ? wqkt : (which == 1) ? (wqkt + 1024 * 1024) : wvt;
    int n0 = (t2 & 31) * 32, k0 = (t2 >> 5) * 32;
    int tx = threadIdx.x & 31, ty = threadIdx.x >> 5;
#pragma unroll
    for (int r = 0; r < 32; r += 8) t[ty + r][tx] = W[(long)(k0 + ty + r) * 1024 + n0 + tx];
    __syncthreads();
#pragma unroll
    for (int r = 0; r < 32; r += 8)
      Wt[(long)(n0 + ty + r) * 1024 + k0 + tx] = (short)f2bf(t[tx][ty + r]);
  } else {                           // concat biases
    int i = (b - 7168) * 256 + threadIdx.x;
    bqk[i] = (i < 1024) ? bq[i] : bk[i - 1024];
  }
}

// ---------------- shared GEMM body (R2-proven): 128x128 tile, BK=32, dbuf+vmcnt(4) ----------------
// MODE 0: plain C = scale*A.Bt^T + bias.
// MODE 1: scores -> writes P_unnorm bf16 = exp(v - M_blk[col]) masked (row>=col),
//         plus per-block column stats (pm = block max, ps = sum exp rel. block max).
// MODE 2: K capped at (bm+1)*128 (PV).
template <typename CT, int MODE>
DEV void gemm_body(short* As0, short* As1, short* Bs0, short* Bs1,
                   const short* A, const short* Bt, CT* C,
                   int K, int lda, int ldbt, int ldc,
                   const float* bias_m, const float* bias_n, float scale,
                   float* pm_out, float* ps_out, int bn, int bm, int bz)
{
  const int kend = (MODE == 2) ? min(K, (bm + 1) * 128) : K;

  const int tid = threadIdx.x;
  const int wid = tid >> 6, lane = tid & 63;
  const int wm = wid >> 1, wn = wid & 1;
  const int rC = lane >> 2;
  const int kB = (lane & 3) * 8;
  const int fr = lane & 15;
  const int fkB = (lane >> 4) * 16;

  const short* Ab = A + (long)bm * 128 * lda + (long)rC * lda + kB;
  const short* Bb = Bt + (long)bn * 128 * ldbt + (long)rC * ldbt + kB;

  f32x4 acc[4][4] = {};

  auto STAGE = [&](short* Asb, short* Bsb, int kk) {
#pragma unroll
    for (int j = 0; j < 2; ++j) {
      int chunk = j * 4 + wid;
      async16(&Asb[chunk * 512], Ab + (long)chunk * 16 * lda + kk);
      async16(&Bsb[chunk * 512], Bb + (long)chunk * 16 * ldbt + kk);
    }
  };

  STAGE(As0, Bs0, 0);
  int cur = 0;
  for (int kk = 0; kk < kend; kk += 32) {
    const short* Ac = cur ? As1 : As0;
    const short* Bc = cur ? Bs1 : Bs0;
    if (kk + 32 < kend) {
      STAGE(cur ? As0 : As1, cur ? Bs0 : Bs1, kk + 32);
      asm volatile("s_waitcnt vmcnt(4)" ::: "memory");
    } else {
      asm volatile("s_waitcnt vmcnt(0)" ::: "memory");
    }
    __builtin_amdgcn_s_barrier();
    __builtin_amdgcn_sched_barrier(0);

    bf16x8 af[4], bf_[4];
#pragma unroll
    for (int i = 0; i < 4; ++i)
      af[i] = *(const bf16x8*)((const char*)Ac + (wm * 64 + i * 16 + fr) * 64 + fkB);
#pragma unroll
    for (int j = 0; j < 4; ++j)
      bf_[j] = *(const bf16x8*)((const char*)Bc + (wn * 64 + j * 16 + fr) * 64 + fkB);
#pragma unroll
    for (int i = 0; i < 4; ++i)
#pragma unroll
      for (int j = 0; j < 4; ++j)
        acc[i][j] = __builtin_amdgcn_mfma_f32_16x16x32_bf16(af[i], bf_[j], acc[i][j], 0, 0, 0);
    __builtin_amdgcn_s_barrier();
    cur ^= 1;
  }

  const int fq = lane >> 4;

  if constexpr (MODE != 1) {
#pragma unroll
    for (int i = 0; i < 4; ++i) {
#pragma unroll
      for (int r = 0; r < 4; ++r) {
        int row = bm * 128 + wm * 64 + i * 16 + fq * 4 + r;
        float bmv = bias_m ? bias_m[row] : 0.f;
#pragma unroll
        for (int j = 0; j < 4; ++j) {
          int col = bn * 128 + wn * 64 + j * 16 + fr;
          float bnv = bias_n ? bias_n[col] : 0.f;
          store_elem(C, (long)row * ldc + col, acc[i][j][r] * scale + bmv + bnv);
        }
      }
    }
  } else {
    // ---- column stats over this block's 128 rows, then P_unnorm bf16 write ----
    float* smax = (float*)As0;     // 256 f
    float* ssum = smax + 256;      // 256 f
    float* mcomb = ssum + 256;     // 128 f: combined block max per col
    const int rbase = bm * 128 + wm * 64 + fq * 4;
#pragma unroll
    for (int j = 0; j < 4; ++j) {
      const int col = bn * 128 + wn * 64 + j * 16 + fr;
      float m = -1e30f;
#pragma unroll
      for (int i = 0; i < 4; ++i)
#pragma unroll
        for (int r = 0; r < 4; ++r) {
          int row = rbase + i * 16 + r;
          float v = acc[i][j][r] * scale;
          m = (row >= col) ? fmaxf(m, v) : m;
        }
      m = fmaxf(m, __shfl_xor(m, 16));
      m = fmaxf(m, __shfl_xor(m, 32));
      float s = 0.f;
#pragma unroll
      for (int i = 0; i < 4; ++i)
#pragma unroll
        for (int r = 0; r < 4; ++r) {
          int row = rbase + i * 16 + r;
          float v = acc[i][j][r] * scale;
          s += (row >= col) ? __expf(v - m) : 0.f;
        }
      s += __shfl_xor(s, 16);
      s += __shfl_xor(s, 32);
      if (fq == 0) {
        smax[wm * 128 + wn * 64 + j * 16 + fr] = m;
        ssum[wm * 128 + wn * 64 + j * 16 + fr] = s;
      }
    }
    __syncthreads();
    if (tid < 128) {
      float m0 = smax[tid], m1 = smax[128 + tid];
      float s0 = ssum[tid], s1 = ssum[128 + tid];
      float M = fmaxf(m0, m1);
      float S2 = (m0 > -1e29f ? s0 * __expf(m0 - M) : 0.f)
               + (m1 > -1e29f ? s1 * __expf(m1 - M) : 0.f);
      long o = ((long)bz * 16 + bm) * 2048 + bn * 128 + tid;
      pm_out[o] = M;
      ps_out[o] = S2;
      mcomb[tid] = M;
    }
    __syncthreads();
#pragma unroll
    for (int j = 0; j < 4; ++j) {
      const int col = bn * 128 + wn * 64 + j * 16 + fr;
      const float Mb = mcomb[wn * 64 + j * 16 + fr];
#pragma unroll
      for (int i = 0; i < 4; ++i)
#pragma unroll
        for (int r = 0; r < 4; ++r) {
          int row = rbase + i * 16 + r;
          float v = acc[i][j][r] * scale;
          short pv = (row >= col) ? (short)f2bf(__expf(v - Mb)) : (short)0;
          C[(long)row * ldc + col] = pv;
        }
    }
  }
}

// plain / PV wrapper. MODE 2 uses LPT ordering (long-K tiles first).
template <typename CT, int MODE>
__global__ __launch_bounds__(256, 2) void gemm_bt(
    const short* __restrict__ A, const short* __restrict__ Bt, CT* __restrict__ C,
    int K, int lda, int ldbt, int ldc,
    long sA, long sBt, long sC,
    const float* __restrict__ bias_m, const float* __restrict__ bias_n, float scale)
{
  __shared__ __align__(16) short lds[4][4096];
  const int bn = blockIdx.x;
  const int bm = (MODE == 2) ? ((int)gridDim.y - 1 - (int)blockIdx.y) : (int)blockIdx.y;
  const int bz = blockIdx.z;
  gemm_body<CT, MODE>(lds[0], lds[1], lds[2], lds[3],
                      A + (long)bz * sA, Bt + (long)bz * sBt, C + (long)bz * sC,
                      K, lda, ldbt, ldc, bias_m, bias_n, scale,
                      nullptr, nullptr, bn, bm, bz);
}

// fat dispatch: scores (compact lower-triangle, fused stats + P_unnorm write)
// + Vt projection. Vt block order: bm fast (8 consecutive blocks share one xb
// slice; wvt 2MB stays L2-hot) -> kills the 8x xb re-fetch seen in R5.
__global__ __launch_bounds__(256, 2) void scores_vt(
    const short* __restrict__ qkb, short* __restrict__ P,
    const short* __restrict__ xb, const short* __restrict__ wvt,
    short* __restrict__ vt, const float* __restrict__ bv,
    float* __restrict__ pmax, float* __restrict__ psum, int ns, int z0)
{
  __shared__ __align__(16) short lds[4][4096];
  const int b = blockIdx.x;
  if (b < ns) {
    const int z = b / 136;               // local batch (indexes P, stats)
    int idx = b - z * 136;
    int bm = 0;
    while ((bm + 1) * (bm + 2) / 2 <= idx) ++bm;   // triangle decode, bn <= bm
    int bn = idx - bm * (bm + 1) / 2;
    const long qoff = (long)(z0 + z) * QKSTR;
    gemm_body<short, 1>(lds[0], lds[1], lds[2], lds[3],
                        qkb + qoff, qkb + qoff + 1024, P + (long)z * PSTR,
                        1024, 2048, 2048, 2048, nullptr, nullptr, 0.03125f,
                        pmax, psum, bn, bm, z);
  } else {
    const int b2 = b - ns;
    const int bm = b2 & 7, bn = b2 >> 3;           // bm fast: xb slice reuse
    gemm_body<short, 0>(lds[0], lds[1], lds[2], lds[3],
                        wvt, xb, vt, 1024, 1024, 1024, 8192,
                        bv, nullptr, 1.f, nullptr, nullptr, bn, bm, 0);
  }
}

// combine 16 row-chunk partials per column -> rescale factors
// F[ch][c] = exp(pm[ch]-M[c]) / sum  (<=1); chunks < c/128 never written/used.
__global__ void colstats_combine(const float* __restrict__ pmax, const float* __restrict__ psum,
                                 float* __restrict__ F) {
  const int bz = blockIdx.y;
  const int c = blockIdx.x * 256 + threadIdx.x;
  const int ch0 = c >> 7;
  float mv[16];
  for (int ch = ch0; ch < 16; ++ch) mv[ch] = pmax[((long)bz * 16 + ch) * 2048 + c];
  float M = -1e30f;
  for (int ch = ch0; ch < 16; ++ch) M = fmaxf(M, mv[ch]);
  float Ssum = 0.f;
  for (int ch = ch0; ch < 16; ++ch) {
    float s = psum[((long)bz * 16 + ch) * 2048 + c];
    Ssum += (mv[ch] > -1e29f) ? s * __expf(mv[ch] - M) : 0.f;
  }
  float R = 1.f / Ssum;
  for (int ch = ch0; ch < 16; ++ch)
    F[((long)bz * 16 + ch) * 2048 + c] = (mv[ch] > -1e29f) ? __expf(mv[ch] - M) * R : 0.f;
}

// P[q][c] *= F[q>>7][c], bf16 in/out; only c < ((q>>7)+1)*128 is live.
__global__ void rescale(short* __restrict__ P, const float* __restrict__ F) {
  const int bz = blockIdx.y;
  const int q = blockIdx.x;
  const int climit = ((q >> 7) + 1) << 7;
  short* Pr = P + ((long)bz * 2048 + q) * 2048;
  const float* Fr = F + ((long)bz * 16 + (q >> 7)) * 2048;
  for (int c = threadIdx.x * 8; c < climit; c += 2048) {
    short8v v = *(short8v*)(Pr + c);
    f32x4 fa = *(const f32x4*)(Fr + c);
    f32x4 fb = *(const f32x4*)(Fr + c + 4);
#pragma unroll
    for (int j = 0; j < 4; ++j) {
      v[j]     = (short)f2bf(bf2f(v[j]) * fa[j]);
      v[4 + j] = (short)f2bf(bf2f(v[4 + j]) * fb[j]);
    }
    *(short8v*)(Pr + c) = v;
  }
}

// ---------------- host side ----------------
extern "C" void kernel_launch(void* const* d_in, const int* in_sizes, int n_in,
                              void* d_out, int out_size, void* d_ws, size_t ws_size,
                              hipStream_t stream) {
  const float* x  = (const float*)d_in[0];
  const float* Wq = (const float*)d_in[1];
  const float* bq = (const float*)d_in[2];
  const float* Wk = (const float*)d_in[3];
  const float* bk = (const float*)d_in[4];
  const float* Wv = (const float*)d_in[5];
  const float* bv = (const float*)d_in[6];
  float* out = (float*)d_out;

  const size_t SZ_XB  = 8192ull * 1024 * 2;
  const size_t SZ_WQK = 2048ull * 1024 * 2;
  const size_t SZ_WT  = 1024ull * 1024 * 2;
  const size_t SZ_QK  = 8192ull * 2048 * 2;
  const size_t SZ_VT  = 1024ull * 8192 * 2;
  const size_t N_ST   = 4ull * 16 * 2048;          // pm / ps / F element counts
  const size_t SZ_STATS = (N_ST * 3 + 2048) * 4;
  const size_t SZ_P1 = 2048ull * 2048 * 2;         // one batch of P (bf16)

  char* p = (char*)d_ws;
  short* xb   = (short*)p; p += SZ_XB;
  short* wqkt = (short*)p; p += SZ_WQK;
  short* wvt  = (short*)p; p += SZ_WT;
  short* qkb  = (short*)p; p += SZ_QK;
  short* vt   = (short*)p; p += SZ_VT;
  float* pmax = (float*)p;
  float* psum = pmax + N_ST;
  float* F    = psum + N_ST;
  float* bqk  = F + N_ST;
  p += SZ_STATS;
  size_t fixed = (size_t)(p - (char*)d_ws);
  int nbuf = (ws_size >= fixed + 4 * SZ_P1) ? 4 : 1;
  short* P = (short*)p;

  // 1) fused prologue (cast + 3 transposes + bias concat), one dispatch
  pre_kernel<<<dim3(7176), dim3(256), 0, stream>>>(x, xb, Wq, Wk, Wv, wqkt, wvt,
                                                   bq, bk, bqk);

  // 2) QK fused projection: C[8192][2048] = xb @ [Wq;Wk]^T + [bq;bk]
  gemm_bt<short, 0><<<dim3(16, 64, 1), dim3(256), 0, stream>>>(
      xb, wqkt, qkb, 1024, 1024, 1024, 2048, 0L, 0L, 0L, nullptr, bqk, 1.f);

  for (int b0 = 0; b0 < 4; b0 += nbuf) {
    const int nz = nbuf;
    const int ns = 136 * nz;
    // 3) scores (+stats, writes P_unnorm bf16) for nz batches; Vt merged on pass 0
    const int nvt = (b0 == 0) ? 512 : 0;
    scores_vt<<<dim3(ns + nvt), dim3(256), 0, stream>>>(
        qkb, P, xb, wvt, vt, bv, pmax, psum, ns, b0);
    // 4) column-softmax factors + bf16 rescale
    colstats_combine<<<dim3(8, nz), dim3(256), 0, stream>>>(pmax, psum, F);
    rescale<<<dim3(2048, nz), dim3(256), 0, stream>>>(P, F);
    // 5) attn = P @ V, K capped per q-tile, LPT block order
    gemm_bt<float, 2><<<dim3(8, 16, nz), dim3(256), 0, stream>>>(
        P, vt + b0 * 2048, out + (long)b0 * OSTR, 2048, 2048, 8192, 1024,
        PSTR, 2048L, OSTR, nullptr, nullptr, 1.f);
  }
}

// Round 8
// 193.816 us; speedup vs baseline: 1.0470x; 1.0470x over previous
//
#include <hip/hip_runtime.h>

#define DEV __device__ __forceinline__

typedef float f32x4 __attribute__((ext_vector_type(4)));
typedef short short4v __attribute__((ext_vector_type(4)));
typedef short short8v __attribute__((ext_vector_type(8)));
typedef __bf16 bf16x8 __attribute__((ext_vector_type(8)));

#define QKSTR (2048L * 2048)
#define PSTR  (2048L * 2048)
#define OSTR  (2048L * 1024)

DEV unsigned short f2bf(float f) {
  unsigned int u = __float_as_uint(f);
  u += 0x7fffu + ((u >> 16) & 1u);   // round-to-nearest-even
  return (unsigned short)(u >> 16);
}
DEV float bf2f(short s) {
  return __uint_as_float(((unsigned int)(unsigned short)s) << 16);
}

DEV void async16(void* lds, const void* g) {
  __builtin_amdgcn_global_load_lds((const __attribute__((address_space(1))) void*)g,
                                   (__attribute__((address_space(3))) void*)lds, 16, 0, 0);
}

DEV void store_elem(float* C, long i, float v) { C[i] = v; }
DEV void store_elem(short* C, long i, float v) { C[i] = (short)f2bf(v); }

// ---------------- fused prologue: cast x, transpose 3 W's, concat biases ----------------
__global__ void pre_kernel(const float* __restrict__ x, short* __restrict__ xb,
                           const float* __restrict__ Wq, const float* __restrict__ Wk,
                           const float* __restrict__ Wv, short* __restrict__ wqkt,
                           short* __restrict__ wvt,
                           const float* __restrict__ bq, const float* __restrict__ bk,
                           float* __restrict__ bqk)
{
  __shared__ float t[32][33];
  const int b = blockIdx.x;
  if (b < 4096) {                    // cast x -> bf16, 8 elems/thread
    long i = ((long)b * 256 + threadIdx.x) * 8;
    f32x4 a = *(const f32x4*)(x + i);
    f32x4 c = *(const f32x4*)(x + i + 4);
    short8v o;
#pragma unroll
    for (int j = 0; j < 4; ++j) { o[j] = (short)f2bf(a[j]); o[4 + j] = (short)f2bf(c[j]); }
    *(short8v*)(xb + i) = o;
  } else if (b < 7168) {             // transpose+cast one 32x32 tile of a W
    int tb = b - 4096;
    int which = tb >> 10;
    int t2 = tb & 1023;
    const float* W = (which == 0) ? Wq : (which == 1) ? Wk : Wv;
    short* Wt = (which == 0) ? wqkt : (which == 1) ? (wqkt + 1024 * 1024) : wvt;
    int n0 = (t2 & 31) * 32, k0 = (t2 >> 5) * 32;
    int tx = threadIdx.x & 31, ty = threadIdx.x >> 5;
#pragma unroll
    for (int r = 0; r < 32; r += 8) t[ty + r][tx] = W[(long)(k0 + ty + r) * 1024 + n0 + tx];
    __syncthreads();
#pragma unroll
    for (int r = 0; r < 32; r += 8)
      Wt[(long)(n0 + ty + r) * 1024 + k0 + tx] = (short)f2bf(t[tx][ty + r]);
  } else {                           // concat biases
    int i = (b - 7168) * 256 + threadIdx.x;
    bqk[i] = (i < 1024) ? bq[i] : bk[i - 1024];
  }
}

// ---------------- shared GEMM body (R2-proven): 128x128 tile, BK=32, dbuf+vmcnt(4) ----------------
// MODE 0: plain C = scale*A.Bt^T + bias.
// MODE 1: scores -> writes P_unnorm bf16 = exp(v - M_blk[col]) masked (row>=col),
//         plus per-block column stats (pm = block max, ps = sum exp rel. block max).
// MODE 2: K capped at (bm+1)*128 (PV).
template <typename CT, int MODE>
DEV void gemm_body(short* As0, short* As1, short* Bs0, short* Bs1,
                   const short* A, const short* Bt, CT* C,
                   int K, int lda, int ldbt, int ldc,
                   const float* bias_m, const float* bias_n, float scale,
                   float* pm_out, float* ps_out, int bn, int bm, int bz)
{
  const int kend = (MODE == 2) ? min(K, (bm + 1) * 128) : K;

  const int tid = threadIdx.x;
  const int wid = tid >> 6, lane = tid & 63;
  const int wm = wid >> 1, wn = wid & 1;
  const int rC = lane >> 2;
  const int kB = (lane & 3) * 8;
  const int fr = lane & 15;
  const int fkB = (lane >> 4) * 16;

  const short* Ab = A + (long)bm * 128 * lda + (long)rC * lda + kB;
  const short* Bb = Bt + (long)bn * 128 * ldbt + (long)rC * ldbt + kB;

  f32x4 acc[4][4] = {};

  auto STAGE = [&](short* Asb, short* Bsb, int kk) {
#pragma unroll
    for (int j = 0; j < 2; ++j) {
      int chunk = j * 4 + wid;
      async16(&Asb[chunk * 512], Ab + (long)chunk * 16 * lda + kk);
      async16(&Bsb[chunk * 512], Bb + (long)chunk * 16 * ldbt + kk);
    }
  };

  STAGE(As0, Bs0, 0);
  int cur = 0;
  for (int kk = 0; kk < kend; kk += 32) {
    const short* Ac = cur ? As1 : As0;
    const short* Bc = cur ? Bs1 : Bs0;
    if (kk + 32 < kend) {
      STAGE(cur ? As0 : As1, cur ? Bs0 : Bs1, kk + 32);
      asm volatile("s_waitcnt vmcnt(4)" ::: "memory");
    } else {
      asm volatile("s_waitcnt vmcnt(0)" ::: "memory");
    }
    __builtin_amdgcn_s_barrier();
    __builtin_amdgcn_sched_barrier(0);

    bf16x8 af[4], bf_[4];
#pragma unroll
    for (int i = 0; i < 4; ++i)
      af[i] = *(const bf16x8*)((const char*)Ac + (wm * 64 + i * 16 + fr) * 64 + fkB);
#pragma unroll
    for (int j = 0; j < 4; ++j)
      bf_[j] = *(const bf16x8*)((const char*)Bc + (wn * 64 + j * 16 + fr) * 64 + fkB);
#pragma unroll
    for (int i = 0; i < 4; ++i)
#pragma unroll
      for (int j = 0; j < 4; ++j)
        acc[i][j] = __builtin_amdgcn_mfma_f32_16x16x32_bf16(af[i], bf_[j], acc[i][j], 0, 0, 0);
    __builtin_amdgcn_s_barrier();
    cur ^= 1;
  }

  const int fq = lane >> 4;

  if constexpr (MODE != 1) {
#pragma unroll
    for (int i = 0; i < 4; ++i) {
#pragma unroll
      for (int r = 0; r < 4; ++r) {
        int row = bm * 128 + wm * 64 + i * 16 + fq * 4 + r;
        float bmv = bias_m ? bias_m[row] : 0.f;
#pragma unroll
        for (int j = 0; j < 4; ++j) {
          int col = bn * 128 + wn * 64 + j * 16 + fr;
          float bnv = bias_n ? bias_n[col] : 0.f;
          store_elem(C, (long)row * ldc + col, acc[i][j][r] * scale + bmv + bnv);
        }
      }
    }
  } else {
    // ---- column stats over this block's 128 rows, then P_unnorm bf16 write ----
    float* smax = (float*)As0;     // 256 f
    float* ssum = smax + 256;      // 256 f
    float* mcomb = ssum + 256;     // 128 f: combined block max per col
    const int rbase = bm * 128 + wm * 64 + fq * 4;
#pragma unroll
    for (int j = 0; j < 4; ++j) {
      const int col = bn * 128 + wn * 64 + j * 16 + fr;
      float m = -1e30f;
#pragma unroll
      for (int i = 0; i < 4; ++i)
#pragma unroll
        for (int r = 0; r < 4; ++r) {
          int row = rbase + i * 16 + r;
          float v = acc[i][j][r] * scale;
          m = (row >= col) ? fmaxf(m, v) : m;
        }
      m = fmaxf(m, __shfl_xor(m, 16));
      m = fmaxf(m, __shfl_xor(m, 32));
      float s = 0.f;
#pragma unroll
      for (int i = 0; i < 4; ++i)
#pragma unroll
        for (int r = 0; r < 4; ++r) {
          int row = rbase + i * 16 + r;
          float v = acc[i][j][r] * scale;
          s += (row >= col) ? __expf(v - m) : 0.f;
        }
      s += __shfl_xor(s, 16);
      s += __shfl_xor(s, 32);
      if (fq == 0) {
        smax[wm * 128 + wn * 64 + j * 16 + fr] = m;
        ssum[wm * 128 + wn * 64 + j * 16 + fr] = s;
      }
    }
    __syncthreads();
    if (tid < 128) {
      float m0 = smax[tid], m1 = smax[128 + tid];
      float s0 = ssum[tid], s1 = ssum[128 + tid];
      float M = fmaxf(m0, m1);
      float S2 = (m0 > -1e29f ? s0 * __expf(m0 - M) : 0.f)
               + (m1 > -1e29f ? s1 * __expf(m1 - M) : 0.f);
      long o = ((long)bz * 16 + bm) * 2048 + bn * 128 + tid;
      pm_out[o] = M;
      ps_out[o] = S2;
      mcomb[tid] = M;
    }
    __syncthreads();
#pragma unroll
    for (int j = 0; j < 4; ++j) {
      const int col = bn * 128 + wn * 64 + j * 16 + fr;
      const float Mb = mcomb[wn * 64 + j * 16 + fr];
#pragma unroll
      for (int i = 0; i < 4; ++i)
#pragma unroll
        for (int r = 0; r < 4; ++r) {
          int row = rbase + i * 16 + r;
          float v = acc[i][j][r] * scale;
          short pv = (row >= col) ? (short)f2bf(__expf(v - Mb)) : (short)0;
          C[(long)row * ldc + col] = pv;
        }
    }
  }
}

// plain / PV wrapper. MODE 2 uses LPT ordering (long-K tiles first).
// 4 blocks/CU: LDS 4x32KB=128<=160KB, VGPR budget 512/4=128.
template <typename CT, int MODE>
__global__ __launch_bounds__(256, 4) void gemm_bt(
    const short* __restrict__ A, const short* __restrict__ Bt, CT* __restrict__ C,
    int K, int lda, int ldbt, int ldc,
    long sA, long sBt, long sC,
    const float* __restrict__ bias_m, const float* __restrict__ bias_n, float scale)
{
  __shared__ __align__(16) short lds[4][4096];
  const int bn = blockIdx.x;
  const int bm = (MODE == 2) ? ((int)gridDim.y - 1 - (int)blockIdx.y) : (int)blockIdx.y;
  const int bz = blockIdx.z;
  gemm_body<CT, MODE>(lds[0], lds[1], lds[2], lds[3],
                      A + (long)bz * sA, Bt + (long)bz * sBt, C + (long)bz * sC,
                      K, lda, ldbt, ldc, bias_m, bias_n, scale,
                      nullptr, nullptr, bn, bm, bz);
}

// fat dispatch: scores (compact lower-triangle, fused stats + P_unnorm write)
// + Vt projection. Vt block order: bn fast (R5-proven: per-bm wvt slice stays
// L2-hot; bm-fast thrashed wvt against scores' qkb working set).
__global__ __launch_bounds__(256, 4) void scores_vt(
    const short* __restrict__ qkb, short* __restrict__ P,
    const short* __restrict__ xb, const short* __restrict__ wvt,
    short* __restrict__ vt, const float* __restrict__ bv,
    float* __restrict__ pmax, float* __restrict__ psum, int ns, int z0)
{
  __shared__ __align__(16) short lds[4][4096];
  const int b = blockIdx.x;
  if (b < ns) {
    const int z = b / 136;               // local batch (indexes P, stats)
    int idx = b - z * 136;
    int bm = 0;
    while ((bm + 1) * (bm + 2) / 2 <= idx) ++bm;   // triangle decode, bn <= bm
    int bn = idx - bm * (bm + 1) / 2;
    const long qoff = (long)(z0 + z) * QKSTR;
    gemm_body<short, 1>(lds[0], lds[1], lds[2], lds[3],
                        qkb + qoff, qkb + qoff + 1024, P + (long)z * PSTR,
                        1024, 2048, 2048, 2048, nullptr, nullptr, 0.03125f,
                        pmax, psum, bn, bm, z);
  } else {
    const int b2 = b - ns;
    const int bn = b2 & 63, bm = b2 >> 6;          // bn fast (R5 order)
    gemm_body<short, 0>(lds[0], lds[1], lds[2], lds[3],
                        wvt, xb, vt, 1024, 1024, 1024, 8192,
                        bv, nullptr, 1.f, nullptr, nullptr, bn, bm, 0);
  }
}

// combine 16 row-chunk partials per column -> rescale factors
// F[ch][c] = exp(pm[ch]-M[c]) / sum  (<=1); chunks < c/128 never written/used.
__global__ void colstats_combine(const float* __restrict__ pmax, const float* __restrict__ psum,
                                 float* __restrict__ F) {
  const int bz = blockIdx.y;
  const int c = blockIdx.x * 256 + threadIdx.x;
  const int ch0 = c >> 7;
  float mv[16];
  for (int ch = ch0; ch < 16; ++ch) mv[ch] = pmax[((long)bz * 16 + ch) * 2048 + c];
  float M = -1e30f;
  for (int ch = ch0; ch < 16; ++ch) M = fmaxf(M, mv[ch]);
  float Ssum = 0.f;
  for (int ch = ch0; ch < 16; ++ch) {
    float s = psum[((long)bz * 16 + ch) * 2048 + c];
    Ssum += (mv[ch] > -1e29f) ? s * __expf(mv[ch] - M) : 0.f;
  }
  float R = 1.f / Ssum;
  for (int ch = ch0; ch < 16; ++ch)
    F[((long)bz * 16 + ch) * 2048 + c] = (mv[ch] > -1e29f) ? __expf(mv[ch] - M) * R : 0.f;
}

// P[q][c] *= F[q>>7][c], bf16 in/out; only c < ((q>>7)+1)*128 is live.
__global__ void rescale(short* __restrict__ P, const float* __restrict__ F) {
  const int bz = blockIdx.y;
  const int q = blockIdx.x;
  const int climit = ((q >> 7) + 1) << 7;
  short* Pr = P + ((long)bz * 2048 + q) * 2048;
  const float* Fr = F + ((long)bz * 16 + (q >> 7)) * 2048;
  for (int c = threadIdx.x * 8; c < climit; c += 2048) {
    short8v v = *(short8v*)(Pr + c);
    f32x4 fa = *(const f32x4*)(Fr + c);
    f32x4 fb = *(const f32x4*)(Fr + c + 4);
#pragma unroll
    for (int j = 0; j < 4; ++j) {
      v[j]     = (short)f2bf(bf2f(v[j]) * fa[j]);
      v[4 + j] = (short)f2bf(bf2f(v[4 + j]) * fb[j]);
    }
    *(short8v*)(Pr + c) = v;
  }
}

// ---------------- host side ----------------
extern "C" void kernel_launch(void* const* d_in, const int* in_sizes, int n_in,
                              void* d_out, int out_size, void* d_ws, size_t ws_size,
                              hipStream_t stream) {
  const float* x  = (const float*)d_in[0];
  const float* Wq = (const float*)d_in[1];
  const float* bq = (const float*)d_in[2];
  const float* Wk = (const float*)d_in[3];
  const float* bk = (const float*)d_in[4];
  const float* Wv = (const float*)d_in[5];
  const float* bv = (const float*)d_in[6];
  float* out = (float*)d_out;

  const size_t SZ_XB  = 8192ull * 1024 * 2;
  const size_t SZ_WQK = 2048ull * 1024 * 2;
  const size_t SZ_WT  = 1024ull * 1024 * 2;
  const size_t SZ_QK  = 8192ull * 2048 * 2;
  const size_t SZ_VT  = 1024ull * 8192 * 2;
  const size_t N_ST   = 4ull * 16 * 2048;          // pm / ps / F element counts
  const size_t SZ_STATS = (N_ST * 3 + 2048) * 4;
  const size_t SZ_P1 = 2048ull * 2048 * 2;         // one batch of P (bf16)

  char* p = (char*)d_ws;
  short* xb   = (short*)p; p += SZ_XB;
  short* wqkt = (short*)p; p += SZ_WQK;
  short* wvt  = (short*)p; p += SZ_WT;
  short* qkb  = (short*)p; p += SZ_QK;
  short* vt   = (short*)p; p += SZ_VT;
  float* pmax = (float*)p;
  float* psum = pmax + N_ST;
  float* F    = psum + N_ST;
  float* bqk  = F + N_ST;
  p += SZ_STATS;
  size_t fixed = (size_t)(p - (char*)d_ws);
  int nbuf = (ws_size >= fixed + 4 * SZ_P1) ? 4 : 1;
  short* P = (short*)p;

  // 1) fused prologue (cast + 3 transposes + bias concat), one dispatch
  pre_kernel<<<dim3(7176), dim3(256), 0, stream>>>(x, xb, Wq, Wk, Wv, wqkt, wvt,
                                                   bq, bk, bqk);

  // 2) QK fused projection: C[8192][2048] = xb @ [Wq;Wk]^T + [bq;bk]
  gemm_bt<short, 0><<<dim3(16, 64, 1), dim3(256), 0, stream>>>(
      xb, wqkt, qkb, 1024, 1024, 1024, 2048, 0L, 0L, 0L, nullptr, bqk, 1.f);

  for (int b0 = 0; b0 < 4; b0 += nbuf) {
    const int nz = nbuf;
    const int ns = 136 * nz;
    // 3) scores (+stats, writes P_unnorm bf16) for nz batches; Vt merged on pass 0
    const int nvt = (b0 == 0) ? 512 : 0;
    scores_vt<<<dim3(ns + nvt), dim3(256), 0, stream>>>(
        qkb, P, xb, wvt, vt, bv, pmax, psum, ns, b0);
    // 4) column-softmax factors + bf16 rescale
    colstats_combine<<<dim3(8, nz), dim3(256), 0, stream>>>(pmax, psum, F);
    rescale<<<dim3(2048, nz), dim3(256), 0, stream>>>(P, F);
    // 5) attn = P @ V, K capped per q-tile, LPT block order
    gemm_bt<float, 2><<<dim3(8, 16, nz), dim3(256), 0, stream>>>(
        P, vt + b0 * 2048, out + (long)b0 * OSTR, 2048, 2048, 8192, 1024,
        PSTR, 2048L, OSTR, nullptr, nullptr, 1.f);
  }
}